// Round 4
// baseline (140.684 us; speedup 1.0000x reference)
//
#include <hip/hip_runtime.h>
#include <hip/hip_bf16.h>

#define VOCAB 10000
#define EMB   16
#define HID   32
#define BATCH 4096
#define TLEN  512

typedef float v2f __attribute__((ext_vector_type(2)));
typedef float v4f __attribute__((ext_vector_type(4)));

// packed fp32 fma: d = a*b + c on 2 lanes-worth of data per instr (gfx90a+)
__device__ __forceinline__ v2f pk_fma(v2f a, v2f b, v2f c) {
    v2f d;
    asm("v_pk_fma_f32 %0, %1, %2, %3" : "=v"(d) : "v"(a), "v"(b), "v"(c));
    return d;
}

// ---------------------------------------------------------------------------
// Kernel 1: P[v][j] = b[j] + sum_e emb[v][e] * Wx[e][j]   (fp32 table in ws)
// ---------------------------------------------------------------------------
__global__ __launch_bounds__(256) void rnn_proj(
    const float* __restrict__ emb, const float* __restrict__ Wx,
    const float* __restrict__ bias, float* __restrict__ P)
{
    int tid = blockIdx.x * 256 + threadIdx.x;
    if (tid >= VOCAB * HID) return;
    int v = tid >> 5;
    int j = tid & 31;
    float acc = bias[j];
    const float* ev = emb + v * EMB;
#pragma unroll
    for (int e = 0; e < EMB; ++e) {
        acc = fmaf(ev[e], Wx[e * HID + j], acc);
    }
    P[tid] = acc;
}

// ---------------------------------------------------------------------------
// Kernel 2: the scan. Wave = 2 batches x 32 j-lanes. Wh column j in VGPRs
// as 16 float2 pairs; h (fp32) in wave-private LDS rows (broadcast float4
// reads, no barriers). Tokens prefetched 3 ahead, P rows 2 ahead.
// __launch_bounds__(256,2): only 2 waves/SIMD exist -> allow ~256 VGPRs,
// prevents the whc/hbuf spill that bloated round-3 (VGPR_Count=32).
// ---------------------------------------------------------------------------
__global__ __launch_bounds__(256, 2) void rnn_scan(
    const int*   __restrict__ x,   const float* __restrict__ P,
    const float* __restrict__ Wh,  const float* __restrict__ Wd,
    const float* __restrict__ bd,  float* __restrict__ out)
{
    __shared__ float h_lds[8][HID];

    const int lane = threadIdx.x & 63;
    const int wave = threadIdx.x >> 6;
    const int half = lane >> 5;
    const int j    = lane & 31;
    const int hb   = wave * 2 + half;          // 0..7 (wave-private row)
    const int b    = blockIdx.x * 8 + hb;

    // Wh column j as pairs: whp[q] = { Wh[2q][j], Wh[2q+1][j] }
    v2f whp[HID / 2];
#pragma unroll
    for (int q = 0; q < HID / 2; ++q) {
        whp[q].x = Wh[(2 * q + 0) * HID + j];
        whp[q].y = Wh[(2 * q + 1) * HID + j];
    }

    h_lds[hb][j] = 0.0f;                        // h0 = 0 (wave-private, no barrier)

    const int* xb = x + b * TLEN;

    // software pipeline: pA = P(t), pB = P(t+1), tokN = token(t+2)
    int   tokN = xb[2];
    float pA = P[xb[0] * HID + j];
    float pB = P[xb[1] * HID + j];

    float hj = 0.0f;
    const float TWO_LOG2E = 2.8853900817779268f; // 2*log2(e)
    const v4f* hrow = (const v4f*)h_lds[hb];

    for (int t = 0; t < TLEN; ++t) {
        // prefetch token(t+3); issue P(t+2) using token loaded last iteration
        int   tokN2 = (t + 3 < TLEN) ? xb[t + 3] : 0;
        float pC    = P[tokN * HID + j];

        // z_j = P[tok][j] + sum_i h_i * Wh[i][j] — packed fp32, 4 accumulators
        v2f a0 = {pA, 0.0f}, a1 = {0.0f, 0.0f}, a2 = {0.0f, 0.0f}, a3 = {0.0f, 0.0f};
#pragma unroll
        for (int q = 0; q < 4; ++q) {
            v4f hv = hrow[2 * q];
            v4f hw = hrow[2 * q + 1];
            a0 = pk_fma((v2f){hv.x, hv.y}, whp[4 * q + 0], a0);
            a1 = pk_fma((v2f){hv.z, hv.w}, whp[4 * q + 1], a1);
            a2 = pk_fma((v2f){hw.x, hw.y}, whp[4 * q + 2], a2);
            a3 = pk_fma((v2f){hw.z, hw.w}, whp[4 * q + 3], a3);
        }
        v2f s = (a0 + a1) + (a2 + a3);
        float z = s.x + s.y;

        // tanh(z) = 1 - 2/(e^{2z}+1); saturates cleanly (inf -> 1, 0 -> -1)
        float e2 = __builtin_amdgcn_exp2f(z * TWO_LOG2E);
        float r  = __builtin_amdgcn_rcpf(e2 + 1.0f);
        hj = fmaf(-2.0f, r, 1.0f);

        h_lds[hb][j] = hj;                      // visible to this wave next iter

        pA = pB; pB = pC; tokN = tokN2;
    }

    // out[b] = sigmoid(sum_j h_j * Wd[j] + bd)
    float s = hj * Wd[j];
#pragma unroll
    for (int off = 16; off > 0; off >>= 1)
        s += __shfl_xor(s, off, 32);            // reduce within 32-lane half
    if (j == 0) {
        float logit = s + bd[0];
        float o = 1.0f / (1.0f + __expf(-logit));
        out[b] = o;                             // fp32 output
    }
}

// ---------------------------------------------------------------------------
extern "C" void kernel_launch(void* const* d_in, const int* in_sizes, int n_in,
                              void* d_out, int out_size, void* d_ws, size_t ws_size,
                              hipStream_t stream)
{
    const int*   x   = (const int*)  d_in[0];
    const float* emb = (const float*)d_in[1];
    const float* Wx  = (const float*)d_in[2];
    const float* Wh  = (const float*)d_in[3];
    const float* bia = (const float*)d_in[4];
    const float* Wd  = (const float*)d_in[5];
    const float* bd  = (const float*)d_in[6];
    float* out = (float*)d_out;

    float* P = (float*)d_ws;                    // VOCAB*HID*4 = 1.28 MB

    rnn_proj<<<(VOCAB * HID + 255) / 256, 256, 0, stream>>>(emb, Wx, bia, P);
    rnn_scan<<<BATCH / 8, 256, 0, stream>>>(x, P, Wh, Wd, bd, out);
}